// Round 1
// baseline (287.499 us; speedup 1.0000x reference)
//
#include <hip/hip_runtime.h>
#include <hip/hip_bf16.h>
#include <cstdint>

// GatedMultiheadAttention: B=2, N=2048, E=1024, H=16, D=64
// R8: attn occupancy + conflict round.
//  - split-K x4 (4096 blocks, 16 kt iters), V read direct from global (L3-res)
//    -> LDS 12.3KB/block, __launch_bounds__(128,5) -> ~20-24 waves/CU (was 16 cap).
//  - P-row perm (prow ^ (prow>>2)&1) fixes the exactly-4.19M 4-way write
//    conflict (all quads aliased one 16-bank half; perm splits them 2+2 = free).
//  - s_setprio(1) around both MFMA clusters (T5, attn-positive per m191).
// ws (48MB): weights 0-8 (LP 1MB overlays dead WQB), XQ/XK/XV 8-32 (-> OPp
// partials 0-2 + AOB alias), QB 32-40, KB 40-48. d_out: VTB low 8MB, partial 3
// high 8MB (both dead before gemm_out's full 16MB write).

#define DEV __device__ __forceinline__
typedef __attribute__((ext_vector_type(8))) short bf16x8;
typedef __attribute__((ext_vector_type(4))) float f32x4;
typedef unsigned short u16;

DEV void async16(const void* g, void* l) {
  __builtin_amdgcn_global_load_lds(
      (const __attribute__((address_space(1))) unsigned int*)g,
      (__attribute__((address_space(3))) unsigned int*)l, 16, 0, 0);
}

DEV u16 bf16_rne(float f) {
  unsigned int u = __builtin_bit_cast(unsigned int, f);
  u += 0x7FFFu + ((u >> 16) & 1u);
  return (u16)(u >> 16);
}

DEV u16 cvt16(float x) {
  __hip_bfloat16 h = __float2bfloat16(x);
  return __builtin_bit_cast(u16, h);
}

DEV unsigned pack2(float lo, float hi) {
  return (unsigned)cvt16(lo) | ((unsigned)cvt16(hi) << 16);
}

// ---------------- one fused cast: q,k,v + 4 weights ----------------
__global__ __launch_bounds__(256) void cast_all(
    const float* __restrict__ q, const float* __restrict__ k, const float* __restrict__ v,
    const float* __restrict__ Wq, const float* __restrict__ Wk,
    const float* __restrict__ Wv, const float* __restrict__ Wo,
    u16* __restrict__ XQ, u16* __restrict__ XK, u16* __restrict__ XV,
    u16* __restrict__ WQB, u16* __restrict__ WKB, u16* __restrict__ WVB,
    u16* __restrict__ WOB) {
  int idx = blockIdx.x * 256 + threadIdx.x;  // one 8-elem item each
  const float* src; u16* dst; int i;
  if      (idx <  524288) { src = q;  dst = XQ;  i = idx; }
  else if (idx < 1048576) { src = k;  dst = XK;  i = idx -  524288; }
  else if (idx < 1572864) { src = v;  dst = XV;  i = idx - 1048576; }
  else if (idx < 1703936) { src = Wq; dst = WQB; i = idx - 1572864; }
  else if (idx < 1835008) { src = Wk; dst = WKB; i = idx - 1703936; }
  else if (idx < 1966080) { src = Wv; dst = WVB; i = idx - 1835008; }
  else                    { src = Wo; dst = WOB; i = idx - 1966080; }
  const float4* p = (const float4*)src + (size_t)i * 2;
  float4 a = p[0], b = p[1];
  union { u16 us[8]; uint4 vv; } u;
  u.us[0] = bf16_rne(a.x); u.us[1] = bf16_rne(a.y);
  u.us[2] = bf16_rne(a.z); u.us[3] = bf16_rne(a.w);
  u.us[4] = bf16_rne(b.x); u.us[5] = bf16_rne(b.y);
  u.us[6] = bf16_rne(b.z); u.us[7] = bf16_rne(b.w);
  ((uint4*)dst)[i] = u.vv;
}

// ---------------- fused QKV projection GEMM (768 blocks, 128x128, dbuf) ------
// seg = bx>>8: 0=Q (gate-scale folded), 1=K, 2=V (writes V^T into d_out).
__global__ __launch_bounds__(256, 3) void gemm_qkv(
    const u16* __restrict__ XQ, const u16* __restrict__ XK, const u16* __restrict__ XV,
    const u16* __restrict__ Wb,  // WQ|WK|WV contiguous, 1M elems apart
    const float* __restrict__ bq, const float* __restrict__ bkb, const float* __restrict__ bv,
    const float* __restrict__ gate,
    u16* __restrict__ QB, u16* __restrict__ KB, u16* __restrict__ VTB) {
  __shared__ __attribute__((aligned(16))) u16 As[2][128 * 32];
  __shared__ __attribute__((aligned(16))) u16 Bs[2][128 * 32];
  const int t = threadIdx.x, lane = t & 63, w = t >> 6;
  const int l15 = lane & 15, quad = lane >> 4;
  const int seg = blockIdx.x >> 8, inner = blockIdx.x & 255;
  const int bm = inner >> 3, bn = inner & 7;
  const int m0 = bm << 7, n0 = bn << 7;
  const u16* A = (seg == 0) ? XQ : (seg == 1) ? XK : XV;
  const u16* W = Wb + (long)seg * 1048576;
  const int wm = (w >> 1) << 6, wn = (w & 1) << 6;
  const int r0 = t >> 2, cc0 = (t & 3) * 8;
  const u16* gA0 = A + (long)(m0 + r0) * 1024 + cc0;
  const u16* gA1 = gA0 + 64 * 1024;
  const u16* gB0 = W + (long)(n0 + r0) * 1024 + cc0;
  const u16* gB1 = gB0 + 64 * 1024;

  async16(gA0, &As[0][t * 8]); async16(gA1, &As[0][(t + 256) * 8]);
  async16(gB0, &Bs[0][t * 8]); async16(gB1, &Bs[0][(t + 256) * 8]);

  f32x4 acc[4][4] = {};
  for (int k0 = 0; k0 < 1024; k0 += 32) {
    const int cur = (k0 >> 5) & 1;
    __syncthreads();
    if (k0 + 32 < 1024) {
      const int kn = k0 + 32, nb = cur ^ 1;
      async16(gA0 + kn, &As[nb][t * 8]); async16(gA1 + kn, &As[nb][(t + 256) * 8]);
      async16(gB0 + kn, &Bs[nb][t * 8]); async16(gB1 + kn, &Bs[nb][(t + 256) * 8]);
    }
    bf16x8 af[4], bfm[4];
#pragma unroll
    for (int i = 0; i < 4; i++)
      af[i] = *(const bf16x8*)&As[cur][(wm + i * 16 + l15) * 32 + quad * 8];
#pragma unroll
    for (int j = 0; j < 4; j++)
      bfm[j] = *(const bf16x8*)&Bs[cur][(wn + j * 16 + l15) * 32 + quad * 8];
#pragma unroll
    for (int i = 0; i < 4; i++)
#pragma unroll
      for (int j = 0; j < 4; j++)
        acc[i][j] = __builtin_amdgcn_mfma_f32_16x16x32_bf16(af[i], bfm[j], acc[i][j], 0, 0, 0);
  }

  if (seg == 2) {  // V: bias + transposed write V^T[(b*1024+col)*2048 + n]
#pragma unroll
    for (int i = 0; i < 4; i++) {
      int token = m0 + wm + i * 16 + quad * 4;
      int bb_ = token >> 11, n = token & 2047;
#pragma unroll
      for (int j = 0; j < 4; j++) {
        int col = n0 + wn + j * 16 + l15;
        float bb = bv[col];
        union { u16 us[4]; uint2 u2; } pk;
#pragma unroll
        for (int r = 0; r < 4; r++) pk.us[r] = bf16_rne(acc[i][j][r] + bb);
        *(uint2*)&VTB[(long)(bb_ * 1024 + col) * 2048 + n] = pk.u2;
      }
    }
  } else {
    const float* bias = seg ? bkb : bq;
    u16* C = seg ? KB : QB;
#pragma unroll
    for (int j = 0; j < 4; j++) {
      int col = n0 + wn + j * 16 + l15;
      float bb = bias[col];
      float scl = 1.f;
      if (seg == 0) {
        float g = gate[col >> 6];
        float sig = 1.f / (1.f + __builtin_amdgcn_exp2f(-g * 1.44269504f));
        scl = sig * 0.125f * 1.44269504f;
      }
#pragma unroll
      for (int i = 0; i < 4; i++) {
        int row = m0 + wm + i * 16 + quad * 4;
#pragma unroll
        for (int r = 0; r < 4; r++)
          C[(long)(row + r) * 1024 + col] = bf16_rne((acc[i][j][r] + bb) * scl);
      }
    }
  }
}

// ---------------- out-proj GEMM: 64x128 tiles, dbuf, fp32 out ----------------
__global__ __launch_bounds__(256, 2) void gemm_out(
    const u16* __restrict__ A, const u16* __restrict__ W,
    const float* __restrict__ bias, float* __restrict__ Cf) {
  __shared__ __attribute__((aligned(16))) u16 As[2][64 * 32];
  __shared__ __attribute__((aligned(16))) u16 Bs[2][128 * 32];
  const int t = threadIdx.x, lane = t & 63, w = t >> 6;
  const int l15 = lane & 15, quad = lane >> 4;
  const int bm = blockIdx.x >> 3, bn = blockIdx.x & 7;
  const int m0 = bm << 6, n0 = bn << 7;
  const int wm = (w >> 1) << 5, wn = (w & 1) << 6;
  const int r0 = t >> 2, cc0 = (t & 3) * 8;
  const u16* gA = A + (long)(m0 + r0) * 1024 + cc0;
  const u16* gB0 = W + (long)(n0 + r0) * 1024 + cc0;
  const u16* gB1 = gB0 + 64 * 1024;

  async16(gA, &As[0][t * 8]);
  async16(gB0, &Bs[0][t * 8]); async16(gB1, &Bs[0][(t + 256) * 8]);

  f32x4 acc[2][4] = {};
  for (int k0 = 0; k0 < 1024; k0 += 32) {
    const int cur = (k0 >> 5) & 1;
    __syncthreads();
    if (k0 + 32 < 1024) {
      const int kn = k0 + 32, nb = cur ^ 1;
      async16(gA + kn, &As[nb][t * 8]);
      async16(gB0 + kn, &Bs[nb][t * 8]); async16(gB1 + kn, &Bs[nb][(t + 256) * 8]);
    }
    bf16x8 af[2], bfm[4];
#pragma unroll
    for (int i = 0; i < 2; i++)
      af[i] = *(const bf16x8*)&As[cur][(wm + i * 16 + l15) * 32 + quad * 8];
#pragma unroll
    for (int j = 0; j < 4; j++)
      bfm[j] = *(const bf16x8*)&Bs[cur][(wn + j * 16 + l15) * 32 + quad * 8];
#pragma unroll
    for (int i = 0; i < 2; i++)
#pragma unroll
      for (int j = 0; j < 4; j++)
        acc[i][j] = __builtin_amdgcn_mfma_f32_16x16x32_bf16(af[i], bfm[j], acc[i][j], 0, 0, 0);
  }

#pragma unroll
  for (int j = 0; j < 4; j++) {
    int col = n0 + wn + j * 16 + l15;
    float bb = bias[col];
#pragma unroll
    for (int i = 0; i < 2; i++) {
      int row = m0 + wm + i * 16 + quad * 4;
#pragma unroll
      for (int r = 0; r < 4; r++)
        Cf[(long)(row + r) * 1024 + col] = acc[i][j][r] + bb;
    }
  }
}

// ---------------- split-K x4 flash attention ----------------
// grid (128,16,2) x 128 thr: bx = qt*4 + ksp; 2 waves x 32 q-rows, BK=32,
// 16 kt iters over 512 keys. K staged in LDS (dbuf, chunk swizzle); V read
// direct from global V^T (L3-resident); P via per-wave LDS with row-perm
// (prow ^ (prow>>2)&1) so the packed b32 writes hit both 16-bank halves.
// LDS 12.3KB -> not the occupancy limit; __launch_bounds__(128,5) -> <=102 VGPR.
__global__ __launch_bounds__(128, 5) void attn_kernel(
    const u16* __restrict__ Q, const u16* __restrict__ Kb,
    const u16* __restrict__ Vt, u16* __restrict__ Op0, u16* __restrict__ Op3,
    float* __restrict__ lp) {
  __shared__ __attribute__((aligned(16))) u16 Ks[2][32 * 64];  // [key][d], 128B rows
  __shared__ __attribute__((aligned(16))) u16 Ps[2][32 * 32];  // per-wave [q][key], 64B rows
  const int t = threadIdx.x, lane = t & 63, w = t >> 6;
  const int l15 = lane & 15, quad = lane >> 4;
  const int qt = blockIdx.x >> 2, ksp = blockIdx.x & 3;
  const int h = blockIdx.y, b = blockIdx.z;
  const int q0 = qt * 64, tok0 = b * 2048, key0 = ksp * 512;
  const u16* Kbase = Kb + (long)tok0 * 1024 + h * 64;
  const u16* Vbase = Vt + (long)(b * 1024 + h * 64) * 2048 + key0;

  // loop-invariant Q fragments (wave rows q0 + w*32 .. +31)
  bf16x8 aq[2][2];
#pragma unroll
  for (int i = 0; i < 2; i++) {
    long row = tok0 + q0 + w * 32 + i * 16 + l15;
#pragma unroll
    for (int ks = 0; ks < 2; ks++)
      aq[i][ks] = *(const bf16x8*)&Q[row * 1024 + h * 64 + ks * 32 + quad * 8];
  }

  // stage K kt=0: chunk ^ ((row>>1)&7) on the GLOBAL chunk so the linear
  // global_load_lds destination stays lane-contiguous.
#pragma unroll
  for (int i = 0; i < 2; i++) {
    int c = i * 128 + t;
    int rk = c >> 3, ck = c & 7, cks = ck ^ ((rk >> 1) & 7);
    async16(&Kbase[(long)(key0 + rk) * 1024 + cks * 8], &Ks[0][c * 8]);
  }

  float l_st[2][4] = {};
  f32x4 O[2][4] = {};

  for (int kt = 0; kt < 16; kt++) {
    const int cur = kt & 1;
    __syncthreads();
    if (kt + 1 < 16) {
      const int k0n = key0 + (kt + 1) * 32, nb = cur ^ 1;
#pragma unroll
      for (int i = 0; i < 2; i++) {
        int c = i * 128 + t;
        int rk = c >> 3, ck = c & 7, cks = ck ^ ((rk >> 1) & 7);
        async16(&Kbase[(long)(k0n + rk) * 1024 + cks * 8], &Ks[nb][c * 8]);
      }
    }

    // S = Q K^T (exp2 domain), pi-interleaved: tile j col l15 = key 2*l15+j
    f32x4 s[2][2] = {};
    __builtin_amdgcn_s_setprio(1);
#pragma unroll
    for (int ks = 0; ks < 2; ks++) {
      bf16x8 bk_[2];
#pragma unroll
      for (int j = 0; j < 2; j++) {
        int rl = 2 * l15 + j;
        bk_[j] = *(const bf16x8*)&Ks[cur][rl * 64 + (((ks * 4 + quad) ^ (l15 & 7))) * 8];
      }
#pragma unroll
      for (int i = 0; i < 2; i++)
#pragma unroll
        for (int j = 0; j < 2; j++)
          s[i][j] = __builtin_amdgcn_mfma_f32_16x16x32_bf16(aq[i][ks], bk_[j], s[i][j], 0, 0, 0);
    }
    __builtin_amdgcn_s_setprio(0);

    // exp2 + deferred l + packed P write (keys 2*l15, 2*l15+1 adjacent).
    // Row perm pr = prow ^ (prow>>2)&1: quads {0,2} and {1,3} land in
    // different 16-bank halves -> 2-way (free) instead of 4-way.
#pragma unroll
    for (int i = 0; i < 2; i++) {
#pragma unroll
      for (int r = 0; r < 4; r++) {
        float p0 = __builtin_amdgcn_exp2f(s[i][0][r]);
        float p1 = __builtin_amdgcn_exp2f(s[i][1][r]);
        l_st[i][r] += p0 + p1;
        const int prow = i * 16 + quad * 4 + r;
        const int pr = prow ^ ((prow >> 2) & 1);
        const int chs = (l15 >> 2) ^ ((prow >> 1) & 3);
        *(unsigned*)&Ps[w][pr * 32 + chs * 8 + (l15 & 3) * 2] = pack2(p0, p1);
      }
    }

    // V fragments direct from global V^T (B-frag rows = d, cols = keys).
    // Issued here (after P writes) so they don't inflate QK-phase VGPR
    // pressure; latency hides under the P ds_write->ds_read turnaround + TLP.
    bf16x8 bv_[4];
#pragma unroll
    for (int dj = 0; dj < 4; dj++)
      bv_[dj] = *(const bf16x8*)&Vbase[(long)(dj * 16 + l15) * 2048 + kt * 32 + quad * 8];

    // O += P @ V (single K=32 MFMA pass)
    {
      bf16x8 ap[2];
#pragma unroll
      for (int i = 0; i < 2; i++) {
        int rl = i * 16 + l15;
        int rp = rl ^ ((rl >> 2) & 1);
        ap[i] = *(const bf16x8*)&Ps[w][rp * 32 + ((quad ^ ((rl >> 1) & 3))) * 8];
      }
      __builtin_amdgcn_s_setprio(1);
#pragma unroll
      for (int i = 0; i < 2; i++)
#pragma unroll
        for (int dj = 0; dj < 4; dj++)
          O[i][dj] = __builtin_amdgcn_mfma_f32_16x16x32_bf16(ap[i], bv_[dj], O[i][dj], 0, 0, 0);
      __builtin_amdgcn_s_setprio(0);
    }
  }

  // epilogue: per-row l reduced over 16 lanes; store raw O (bf16) + l (f32)
  u16* dst = (ksp == 3) ? Op3 : (Op0 + (long)ksp * 4194304);
#pragma unroll
  for (int i = 0; i < 2; i++) {
#pragma unroll
    for (int r = 0; r < 4; r++) {
      float ls = l_st[i][r];
      ls += __shfl_xor(ls, 1); ls += __shfl_xor(ls, 2);
      ls += __shfl_xor(ls, 4); ls += __shfl_xor(ls, 8);
      long row = tok0 + q0 + w * 32 + i * 16 + quad * 4 + r;
#pragma unroll
      for (int dj = 0; dj < 4; dj++)
        dst[row * 1024 + h * 64 + dj * 16 + l15] = cvt16(O[i][dj][r]);
      if (l15 == 0) lp[ksp * 65536 + (int)row * 16 + h] = ls;
    }
  }
}

// ---------------- merge split-K partials: AO = (O0+O1+O2+O3)/(l0+..+l3) -----
// AO aliases partial 0 (thread idx reads chunk idx before writing it; 1:1 map).
__global__ __launch_bounds__(256) void merge_kernel(
    const u16* __restrict__ Op0, const u16* __restrict__ Op3,
    const float* __restrict__ lp, u16* __restrict__ AO) {
  int idx = blockIdx.x * 256 + threadIdx.x;  // 524288 chunks of 8 elems
  int tok = idx >> 7, rem = idx & 127, h = rem >> 3;
  int li = tok * 16 + h;
  float inv = 1.f / (lp[li] + lp[65536 + li] + lp[131072 + li] + lp[196608 + li]);
  union U { uint4 v; u16 us[8]; };
  U a0, a1, a2, a3, uo;
  a0.v = ((const uint4*)Op0)[idx];
  a1.v = ((const uint4*)Op0)[idx + 524288];
  a2.v = ((const uint4*)Op0)[idx + 1048576];
  a3.v = ((const uint4*)Op3)[idx];
#pragma unroll
  for (int j = 0; j < 8; j++) {
    float f0 = __builtin_bit_cast(float, (unsigned)((unsigned)a0.us[j] << 16));
    float f1 = __builtin_bit_cast(float, (unsigned)((unsigned)a1.us[j] << 16));
    float f2 = __builtin_bit_cast(float, (unsigned)((unsigned)a2.us[j] << 16));
    float f3 = __builtin_bit_cast(float, (unsigned)((unsigned)a3.us[j] << 16));
    uo.us[j] = cvt16((f0 + f1 + f2 + f3) * inv);
  }
  ((uint4*)AO)[idx] = uo.v;
}

extern "C" void kernel_launch(void* const* d_in, const int* in_sizes, int n_in,
                              void* d_out, int out_size, void* d_ws, size_t ws_size,
                              hipStream_t stream) {
  const float* q  = (const float*)d_in[0];
  const float* k  = (const float*)d_in[1];
  const float* v  = (const float*)d_in[2];
  const float* Wq = (const float*)d_in[3];
  const float* bq = (const float*)d_in[4];
  const float* Wk = (const float*)d_in[5];
  const float* bk = (const float*)d_in[6];
  const float* Wv = (const float*)d_in[7];
  const float* bv = (const float*)d_in[8];
  const float* Wo = (const float*)d_in[9];
  const float* bo = (const float*)d_in[10];
  const float* gate = (const float*)d_in[11];
  float* out = (float*)d_out;
  char* ws = (char*)d_ws;

  const size_t MB = 1u << 20;
  u16* WQB = (u16*)(ws + 0 * MB);   // WQ|WK|WV|WO contiguous (2MB each)
  u16* WKB = (u16*)(ws + 2 * MB);
  u16* WVB = (u16*)(ws + 4 * MB);
  u16* WOB = (u16*)(ws + 6 * MB);
  u16* XQ  = (u16*)(ws + 8 * MB);
  u16* XK  = (u16*)(ws + 16 * MB);
  u16* XV  = (u16*)(ws + 24 * MB);
  u16* QB  = (u16*)(ws + 32 * MB);
  u16* KB  = (u16*)(ws + 40 * MB);
  u16* OPp  = (u16*)(ws + 8 * MB);             // partials 0-2 (24MB, over dead XQ/XK/XV)
  u16* OPd3 = (u16*)((char*)d_out + 8 * MB);   // partial 3 in d_out's upper half
  float* LP = (float*)(ws + 0 * MB);           // 1MB partial l (over dead WQB)
  u16* AOB = (u16*)(ws + 8 * MB);              // == partial 0 (merge self-overwrites)
  u16* VTB = (u16*)d_out;                      // d_out low 8MB as V^T scratch

  cast_all<<<8192, 256, 0, stream>>>(q, k, v, Wq, Wk, Wv, Wo,
                                     XQ, XK, XV, WQB, WKB, WVB, WOB);
  gemm_qkv<<<768, 256, 0, stream>>>(XQ, XK, XV, WQB, bq, bk, bv, gate, QB, KB, VTB);
  attn_kernel<<<dim3(128, 16, 2), 128, 0, stream>>>(QB, KB, VTB, OPp, OPd3, LP);
  merge_kernel<<<2048, 256, 0, stream>>>(OPp, OPd3, LP, AOB);
  gemm_out<<<512, 256, 0, stream>>>(AOB, WOB, bo, out);
}

// Round 2
// 238.752 us; speedup vs baseline: 1.2042x; 1.2042x over previous
//
#include <hip/hip_runtime.h>
#include <hip/hip_bf16.h>
#include <cstdint>

// GatedMultiheadAttention: B=2, N=2048, E=1024, H=16, D=64
// R9 = R7 structure (split-K x2, K+V LDS-staged dbuf) + swapped QK^T:
//  - mfma(K_frag, Q_frag) -> S^T with lane q=l15, keys 8*quad+2r+j (the
//    pi-interleave kappa(j,x)=2x+j makes each lane hold exactly its PV
//    A-frag keys) -> P packed in-register, NO P LDS round-trip at all.
//  - deletes Ps (LDS 20.5->16KB -> 10 blocks/CU = 20 waves), all P bank
//    conflicts (was 4.19M), 8 ds_write + 2 ds_read per iter per wave.
//  - R8 lesson: V stays LDS-staged (direct-global V frags are uncoalesced
//    64-line gathers on the critical path -> 2x regression).
// ws (48MB): weights 0-8 (LP overlays dead WQB), XQ 8-16 (->AOB),
// XK/XV 16-32 (->OPp), QB 32-40, KB 40-48. VTB = d_out (dead until final GEMM).

#define DEV __device__ __forceinline__
typedef __attribute__((ext_vector_type(8))) short bf16x8;
typedef __attribute__((ext_vector_type(4))) float f32x4;
typedef unsigned short u16;

DEV void async16(const void* g, void* l) {
  __builtin_amdgcn_global_load_lds(
      (const __attribute__((address_space(1))) unsigned int*)g,
      (__attribute__((address_space(3))) unsigned int*)l, 16, 0, 0);
}

DEV u16 bf16_rne(float f) {
  unsigned int u = __builtin_bit_cast(unsigned int, f);
  u += 0x7FFFu + ((u >> 16) & 1u);
  return (u16)(u >> 16);
}

DEV u16 cvt16(float x) {
  __hip_bfloat16 h = __float2bfloat16(x);
  return __builtin_bit_cast(u16, h);
}

DEV unsigned pack2(float lo, float hi) {
  return (unsigned)cvt16(lo) | ((unsigned)cvt16(hi) << 16);
}

// ---------------- one fused cast: q,k,v + 4 weights ----------------
__global__ __launch_bounds__(256) void cast_all(
    const float* __restrict__ q, const float* __restrict__ k, const float* __restrict__ v,
    const float* __restrict__ Wq, const float* __restrict__ Wk,
    const float* __restrict__ Wv, const float* __restrict__ Wo,
    u16* __restrict__ XQ, u16* __restrict__ XK, u16* __restrict__ XV,
    u16* __restrict__ WQB, u16* __restrict__ WKB, u16* __restrict__ WVB,
    u16* __restrict__ WOB) {
  int idx = blockIdx.x * 256 + threadIdx.x;  // one 8-elem item each
  const float* src; u16* dst; int i;
  if      (idx <  524288) { src = q;  dst = XQ;  i = idx; }
  else if (idx < 1048576) { src = k;  dst = XK;  i = idx -  524288; }
  else if (idx < 1572864) { src = v;  dst = XV;  i = idx - 1048576; }
  else if (idx < 1703936) { src = Wq; dst = WQB; i = idx - 1572864; }
  else if (idx < 1835008) { src = Wk; dst = WKB; i = idx - 1703936; }
  else if (idx < 1966080) { src = Wv; dst = WVB; i = idx - 1835008; }
  else                    { src = Wo; dst = WOB; i = idx - 1966080; }
  const float4* p = (const float4*)src + (size_t)i * 2;
  float4 a = p[0], b = p[1];
  union { u16 us[8]; uint4 vv; } u;
  u.us[0] = bf16_rne(a.x); u.us[1] = bf16_rne(a.y);
  u.us[2] = bf16_rne(a.z); u.us[3] = bf16_rne(a.w);
  u.us[4] = bf16_rne(b.x); u.us[5] = bf16_rne(b.y);
  u.us[6] = bf16_rne(b.z); u.us[7] = bf16_rne(b.w);
  ((uint4*)dst)[i] = u.vv;
}

// ---------------- fused QKV projection GEMM (768 blocks, 128x128, dbuf) ------
// seg = bx>>8: 0=Q (gate-scale folded), 1=K, 2=V (writes V^T into d_out).
__global__ __launch_bounds__(256, 3) void gemm_qkv(
    const u16* __restrict__ XQ, const u16* __restrict__ XK, const u16* __restrict__ XV,
    const u16* __restrict__ Wb,  // WQ|WK|WV contiguous, 1M elems apart
    const float* __restrict__ bq, const float* __restrict__ bkb, const float* __restrict__ bv,
    const float* __restrict__ gate,
    u16* __restrict__ QB, u16* __restrict__ KB, u16* __restrict__ VTB) {
  __shared__ __attribute__((aligned(16))) u16 As[2][128 * 32];
  __shared__ __attribute__((aligned(16))) u16 Bs[2][128 * 32];
  const int t = threadIdx.x, lane = t & 63, w = t >> 6;
  const int l15 = lane & 15, quad = lane >> 4;
  const int seg = blockIdx.x >> 8, inner = blockIdx.x & 255;
  const int bm = inner >> 3, bn = inner & 7;
  const int m0 = bm << 7, n0 = bn << 7;
  const u16* A = (seg == 0) ? XQ : (seg == 1) ? XK : XV;
  const u16* W = Wb + (long)seg * 1048576;
  const int wm = (w >> 1) << 6, wn = (w & 1) << 6;
  const int r0 = t >> 2, cc0 = (t & 3) * 8;
  const u16* gA0 = A + (long)(m0 + r0) * 1024 + cc0;
  const u16* gA1 = gA0 + 64 * 1024;
  const u16* gB0 = W + (long)(n0 + r0) * 1024 + cc0;
  const u16* gB1 = gB0 + 64 * 1024;

  async16(gA0, &As[0][t * 8]); async16(gA1, &As[0][(t + 256) * 8]);
  async16(gB0, &Bs[0][t * 8]); async16(gB1, &Bs[0][(t + 256) * 8]);

  f32x4 acc[4][4] = {};
  for (int k0 = 0; k0 < 1024; k0 += 32) {
    const int cur = (k0 >> 5) & 1;
    __syncthreads();
    if (k0 + 32 < 1024) {
      const int kn = k0 + 32, nb = cur ^ 1;
      async16(gA0 + kn, &As[nb][t * 8]); async16(gA1 + kn, &As[nb][(t + 256) * 8]);
      async16(gB0 + kn, &Bs[nb][t * 8]); async16(gB1 + kn, &Bs[nb][(t + 256) * 8]);
    }
    bf16x8 af[4], bfm[4];
#pragma unroll
    for (int i = 0; i < 4; i++)
      af[i] = *(const bf16x8*)&As[cur][(wm + i * 16 + l15) * 32 + quad * 8];
#pragma unroll
    for (int j = 0; j < 4; j++)
      bfm[j] = *(const bf16x8*)&Bs[cur][(wn + j * 16 + l15) * 32 + quad * 8];
#pragma unroll
    for (int i = 0; i < 4; i++)
#pragma unroll
      for (int j = 0; j < 4; j++)
        acc[i][j] = __builtin_amdgcn_mfma_f32_16x16x32_bf16(af[i], bfm[j], acc[i][j], 0, 0, 0);
  }

  if (seg == 2) {  // V: bias + transposed write V^T[(b*1024+col)*2048 + n]
#pragma unroll
    for (int i = 0; i < 4; i++) {
      int token = m0 + wm + i * 16 + quad * 4;
      int bb_ = token >> 11, n = token & 2047;
#pragma unroll
      for (int j = 0; j < 4; j++) {
        int col = n0 + wn + j * 16 + l15;
        float bb = bv[col];
        union { u16 us[4]; uint2 u2; } pk;
#pragma unroll
        for (int r = 0; r < 4; r++) pk.us[r] = bf16_rne(acc[i][j][r] + bb);
        *(uint2*)&VTB[(long)(bb_ * 1024 + col) * 2048 + n] = pk.u2;
      }
    }
  } else {
    const float* bias = seg ? bkb : bq;
    u16* C = seg ? KB : QB;
#pragma unroll
    for (int j = 0; j < 4; j++) {
      int col = n0 + wn + j * 16 + l15;
      float bb = bias[col];
      float scl = 1.f;
      if (seg == 0) {
        float g = gate[col >> 6];
        float sig = 1.f / (1.f + __builtin_amdgcn_exp2f(-g * 1.44269504f));
        scl = sig * 0.125f * 1.44269504f;
      }
#pragma unroll
      for (int i = 0; i < 4; i++) {
        int row = m0 + wm + i * 16 + quad * 4;
#pragma unroll
        for (int r = 0; r < 4; r++)
          C[(long)(row + r) * 1024 + col] = bf16_rne((acc[i][j][r] + bb) * scl);
      }
    }
  }
}

// ---------------- out-proj GEMM: 64x128 tiles, dbuf, fp32 out ----------------
__global__ __launch_bounds__(256, 2) void gemm_out(
    const u16* __restrict__ A, const u16* __restrict__ W,
    const float* __restrict__ bias, float* __restrict__ Cf) {
  __shared__ __attribute__((aligned(16))) u16 As[2][64 * 32];
  __shared__ __attribute__((aligned(16))) u16 Bs[2][128 * 32];
  const int t = threadIdx.x, lane = t & 63, w = t >> 6;
  const int l15 = lane & 15, quad = lane >> 4;
  const int bm = blockIdx.x >> 3, bn = blockIdx.x & 7;
  const int m0 = bm << 6, n0 = bn << 7;
  const int wm = (w >> 1) << 5, wn = (w & 1) << 6;
  const int r0 = t >> 2, cc0 = (t & 3) * 8;
  const u16* gA = A + (long)(m0 + r0) * 1024 + cc0;
  const u16* gB0 = W + (long)(n0 + r0) * 1024 + cc0;
  const u16* gB1 = gB0 + 64 * 1024;

  async16(gA, &As[0][t * 8]);
  async16(gB0, &Bs[0][t * 8]); async16(gB1, &Bs[0][(t + 256) * 8]);

  f32x4 acc[2][4] = {};
  for (int k0 = 0; k0 < 1024; k0 += 32) {
    const int cur = (k0 >> 5) & 1;
    __syncthreads();
    if (k0 + 32 < 1024) {
      const int kn = k0 + 32, nb = cur ^ 1;
      async16(gA + kn, &As[nb][t * 8]);
      async16(gB0 + kn, &Bs[nb][t * 8]); async16(gB1 + kn, &Bs[nb][(t + 256) * 8]);
    }
    bf16x8 af[2], bfm[4];
#pragma unroll
    for (int i = 0; i < 2; i++)
      af[i] = *(const bf16x8*)&As[cur][(wm + i * 16 + l15) * 32 + quad * 8];
#pragma unroll
    for (int j = 0; j < 4; j++)
      bfm[j] = *(const bf16x8*)&Bs[cur][(wn + j * 16 + l15) * 32 + quad * 8];
#pragma unroll
    for (int i = 0; i < 2; i++)
#pragma unroll
      for (int j = 0; j < 4; j++)
        acc[i][j] = __builtin_amdgcn_mfma_f32_16x16x32_bf16(af[i], bfm[j], acc[i][j], 0, 0, 0);
  }

#pragma unroll
  for (int j = 0; j < 4; j++) {
    int col = n0 + wn + j * 16 + l15;
    float bb = bias[col];
#pragma unroll
    for (int i = 0; i < 2; i++) {
      int row = m0 + wm + i * 16 + quad * 4;
#pragma unroll
      for (int r = 0; r < 4; r++)
        Cf[(long)(row + r) * 1024 + col] = acc[i][j][r] + bb;
    }
  }
}

// ---------------- split-K flash attention, swapped QK^T, P in-register ------
// grid (64,16,2) x 128 thr: bx = qt*2 + ksplit; 2 waves x 32 q-rows, BK=32.
// QK: s[i][j] = mfma(A=K_frag(row 2*l15+j), B=Q_frag) = S^T; lane (l15,quad)
// holds q = i*16+l15, keys kt*32 + 8*quad + 2r + j -> exactly the PV A-frag
// keys (8*quad..+7). exp2 + pack2 in-register -> ap[i]; no P LDS.
// LDS 16KB -> 10 blocks/CU (20 waves); launch_bounds(128,5) caps VGPR ~102.
__global__ __launch_bounds__(128, 5) void attn_kernel(
    const u16* __restrict__ Q, const u16* __restrict__ Kb,
    const u16* __restrict__ Vt, u16* __restrict__ Op, float* __restrict__ lp) {
  __shared__ __attribute__((aligned(16))) u16 Ks[2][32 * 64];  // [key][d], 128B rows
  __shared__ __attribute__((aligned(16))) u16 Vs[2][64 * 32];  // [d][key], 64B rows
  const int t = threadIdx.x, lane = t & 63, w = t >> 6;
  const int l15 = lane & 15, quad = lane >> 4;
  const int qt = blockIdx.x >> 1, ksp = blockIdx.x & 1;
  const int h = blockIdx.y, b = blockIdx.z;
  const int q0 = qt * 64, tok0 = b * 2048, key0 = ksp * 1024;
  const u16* Kbase = Kb + (long)tok0 * 1024 + h * 64;
  const u16* Vbase = Vt + (long)(b * 1024 + h * 64) * 2048;

  // loop-invariant Q fragments (B operand; wave rows q0 + w*32 .. +31)
  bf16x8 aq[2][2];
#pragma unroll
  for (int i = 0; i < 2; i++) {
    long row = tok0 + q0 + w * 32 + i * 16 + l15;
#pragma unroll
    for (int ks = 0; ks < 2; ks++)
      aq[i][ks] = *(const bf16x8*)&Q[row * 1024 + h * 64 + ks * 32 + quad * 8];
  }

  // stage kt=0. K: chunk ^ ((row>>1)&7); V: chunk ^ ((row>>1)&3). Swizzle on
  // the GLOBAL chunk so global_load_lds lane-contiguity holds.
#pragma unroll
  for (int i = 0; i < 2; i++) {
    int c = i * 128 + t;
    int rk = c >> 3, ck = c & 7, cks = ck ^ ((rk >> 1) & 7);
    async16(&Kbase[(long)(key0 + rk) * 1024 + cks * 8], &Ks[0][c * 8]);
    int rv = c >> 2, cv = c & 3, cvs = cv ^ ((rv >> 1) & 3);
    async16(&Vbase[(long)rv * 2048 + key0 + cvs * 8], &Vs[0][c * 8]);
  }

  float l_st[2] = {};   // per-lane: q = i*16+l15, partial over this lane's keys
  f32x4 O[2][4] = {};

  for (int kt = 0; kt < 32; kt++) {
    const int cur = kt & 1;
    __syncthreads();
    if (kt + 1 < 32) {
      const int k0n = key0 + (kt + 1) * 32, nb = cur ^ 1;
#pragma unroll
      for (int i = 0; i < 2; i++) {
        int c = i * 128 + t;
        int rk = c >> 3, ck = c & 7, cks = ck ^ ((rk >> 1) & 7);
        async16(&Kbase[(long)(k0n + rk) * 1024 + cks * 8], &Ks[nb][c * 8]);
        int rv = c >> 2, cv = c & 3, cvs = cv ^ ((rv >> 1) & 3);
        async16(&Vbase[(long)rv * 2048 + k0n + cvs * 8], &Vs[nb][c * 8]);
      }
    }

    // S^T = K Q^T (exp2 domain): A = K rows 2*l15+j, B = aq.
    f32x4 s[2][2] = {};
    __builtin_amdgcn_s_setprio(1);
#pragma unroll
    for (int ks = 0; ks < 2; ks++) {
      bf16x8 bk_[2];
#pragma unroll
      for (int j = 0; j < 2; j++) {
        int rl = 2 * l15 + j;
        bk_[j] = *(const bf16x8*)&Ks[cur][rl * 64 + (((ks * 4 + quad) ^ (l15 & 7))) * 8];
      }
#pragma unroll
      for (int i = 0; i < 2; i++)
#pragma unroll
        for (int j = 0; j < 2; j++)
          s[i][j] = __builtin_amdgcn_mfma_f32_16x16x32_bf16(bk_[j], aq[i][ks], s[i][j], 0, 0, 0);
    }
    __builtin_amdgcn_s_setprio(0);

    // exp2 + in-register pack: ap[i] word r = keys (8q+2r, 8q+2r+1)
    bf16x8 ap[2];
#pragma unroll
    for (int i = 0; i < 2; i++) {
      union { unsigned uw[4]; bf16x8 v8; } pw;
#pragma unroll
      for (int r = 0; r < 4; r++) {
        float p0 = __builtin_amdgcn_exp2f(s[i][0][r]);
        float p1 = __builtin_amdgcn_exp2f(s[i][1][r]);
        l_st[i] += p0 + p1;
        pw.uw[r] = pack2(p0, p1);
      }
      ap[i] = pw.v8;
    }

    // V fragments from LDS; O += P @ V (single K=32 MFMA pass)
    bf16x8 bv_[4];
#pragma unroll
    for (int dj = 0; dj < 4; dj++) {
      int rl = dj * 16 + l15;
      bv_[dj] = *(const bf16x8*)&Vs[cur][rl * 32 + ((quad ^ ((rl >> 1) & 3))) * 8];
    }
    __builtin_amdgcn_s_setprio(1);
#pragma unroll
    for (int i = 0; i < 2; i++)
#pragma unroll
      for (int dj = 0; dj < 4; dj++)
        O[i][dj] = __builtin_amdgcn_mfma_f32_16x16x32_bf16(ap[i], bv_[dj], O[i][dj], 0, 0, 0);
    __builtin_amdgcn_s_setprio(0);
  }

  // epilogue: l reduced across quads (lanes l15, +16, +32, +48); store O + l
#pragma unroll
  for (int i = 0; i < 2; i++) {
    float ls = l_st[i];
    ls += __shfl_xor(ls, 16); ls += __shfl_xor(ls, 32);
    if (quad == 0) {
      long qrow = tok0 + q0 + w * 32 + i * 16 + l15;
      lp[ksp * 65536 + (int)qrow * 16 + h] = ls;
    }
#pragma unroll
    for (int r = 0; r < 4; r++) {
      long row = tok0 + q0 + w * 32 + i * 16 + quad * 4 + r;
#pragma unroll
      for (int dj = 0; dj < 4; dj++)
        Op[(long)ksp * 4194304 + row * 1024 + h * 64 + dj * 16 + l15] = cvt16(O[i][dj][r]);
    }
  }
}

// ---------------- merge split-K partials: AO = (O0+O1)/(l0+l1) ----------------
__global__ __launch_bounds__(256) void merge_kernel(
    const u16* __restrict__ Op, const float* __restrict__ lp,
    u16* __restrict__ AO) {
  int idx = blockIdx.x * 256 + threadIdx.x;  // 524288 chunks of 8 elems
  int tok = idx >> 7, rem = idx & 127, h = rem >> 3;
  float inv = 1.f / (lp[tok * 16 + h] + lp[65536 + tok * 16 + h]);
  union { uint4 v; u16 us[8]; } ua, ub, uo;
  ua.v = ((const uint4*)Op)[idx];
  ub.v = ((const uint4*)Op)[idx + 524288];
#pragma unroll
  for (int j = 0; j < 8; j++) {
    float fa = __builtin_bit_cast(float, (unsigned)((unsigned)ua.us[j] << 16));
    float fb = __builtin_bit_cast(float, (unsigned)((unsigned)ub.us[j] << 16));
    uo.us[j] = cvt16((fa + fb) * inv);
  }
  ((uint4*)AO)[idx] = uo.v;
}

extern "C" void kernel_launch(void* const* d_in, const int* in_sizes, int n_in,
                              void* d_out, int out_size, void* d_ws, size_t ws_size,
                              hipStream_t stream) {
  const float* q  = (const float*)d_in[0];
  const float* k  = (const float*)d_in[1];
  const float* v  = (const float*)d_in[2];
  const float* Wq = (const float*)d_in[3];
  const float* bq = (const float*)d_in[4];
  const float* Wk = (const float*)d_in[5];
  const float* bk = (const float*)d_in[6];
  const float* Wv = (const float*)d_in[7];
  const float* bv = (const float*)d_in[8];
  const float* Wo = (const float*)d_in[9];
  const float* bo = (const float*)d_in[10];
  const float* gate = (const float*)d_in[11];
  float* out = (float*)d_out;
  char* ws = (char*)d_ws;

  const size_t MB = 1u << 20;
  u16* WQB = (u16*)(ws + 0 * MB);   // WQ|WK|WV|WO contiguous (2MB each)
  u16* WKB = (u16*)(ws + 2 * MB);
  u16* WVB = (u16*)(ws + 4 * MB);
  u16* WOB = (u16*)(ws + 6 * MB);
  u16* XQ  = (u16*)(ws + 8 * MB);
  u16* XK  = (u16*)(ws + 16 * MB);
  u16* XV  = (u16*)(ws + 24 * MB);
  u16* QB  = (u16*)(ws + 32 * MB);
  u16* KB  = (u16*)(ws + 40 * MB);
  u16* AOB = (u16*)(ws + 8 * MB);     // over dead XQ
  u16* OPp = (u16*)(ws + 16 * MB);    // 16MB partial O (over dead XK/XV)
  float* LP = (float*)(ws + 0 * MB);  // 512KB partial l (over dead WQB)
  u16* VTB = (u16*)d_out;             // d_out as scratch until final GEMM

  cast_all<<<8192, 256, 0, stream>>>(q, k, v, Wq, Wk, Wv, Wo,
                                     XQ, XK, XV, WQB, WKB, WVB, WOB);
  gemm_qkv<<<768, 256, 0, stream>>>(XQ, XK, XV, WQB, bq, bk, bv, gate, QB, KB, VTB);
  attn_kernel<<<dim3(64, 16, 2), 128, 0, stream>>>(QB, KB, VTB, OPp, LP);
  merge_kernel<<<2048, 256, 0, stream>>>(OPp, LP, AOB);
  gemm_out<<<512, 256, 0, stream>>>(AOB, WOB, bo, out);
}

// Round 3
// 232.607 us; speedup vs baseline: 1.2360x; 1.0264x over previous
//
#include <hip/hip_runtime.h>
#include <hip/hip_bf16.h>
#include <cstdint>

// GatedMultiheadAttention: B=2, N=2048, E=1024, H=16, D=64
// R10 = R9 + three changes:
//  - attn: v_cvt_pk_bf16_f32 asm for P-pack (1 instr vs ~10 VALU per pair;
//    VALUBusy 40% was > MfmaUtil 23% -> pack was on the critical path).
//  - attn: split-K x4 (grid 4096, 16 iters) to fill the 10-block/CU LDS
//    headroom (was grid-capped at 8). V stays LDS-staged (R8 lesson).
//    4-partial merge wiring reused from R8 (partials 0-2 over XQ/XK/XV,
//    partial 3 in d_out high 8MB, LP 1MB over dead WQB).
//  - gemm_qkv/gemm_out: T1 XCD bm-stripe swizzle (default bx%8 placement put
//    one bn per XCD -> every XCD streamed all of A: FETCH 101MB vs 30 ideal).
// ws (48MB): weights 0-8, XQ 8-16, XK/XV 16-32 (-> OPp partials + AOB),
// QB 32-40, KB 40-48. d_out: VTB low 8MB, partial3 high 8MB.

#define DEV __device__ __forceinline__
typedef __attribute__((ext_vector_type(8))) short bf16x8;
typedef __attribute__((ext_vector_type(4))) float f32x4;
typedef unsigned short u16;

DEV void async16(const void* g, void* l) {
  __builtin_amdgcn_global_load_lds(
      (const __attribute__((address_space(1))) unsigned int*)g,
      (__attribute__((address_space(3))) unsigned int*)l, 16, 0, 0);
}

DEV u16 bf16_rne(float f) {
  unsigned int u = __builtin_bit_cast(unsigned int, f);
  u += 0x7FFFu + ((u >> 16) & 1u);
  return (u16)(u >> 16);
}

DEV u16 cvt16(float x) {
  __hip_bfloat16 h = __float2bfloat16(x);
  return __builtin_bit_cast(u16, h);
}

// packed RNE f32x2 -> bf16x2 in one VALU op (low = lo, high = hi)
DEV unsigned cvtpk(float lo, float hi) {
  unsigned r;
  asm("v_cvt_pk_bf16_f32 %0, %1, %2" : "=v"(r) : "v"(lo), "v"(hi));
  return r;
}

// ---------------- one fused cast: q,k,v + 4 weights ----------------
__global__ __launch_bounds__(256) void cast_all(
    const float* __restrict__ q, const float* __restrict__ k, const float* __restrict__ v,
    const float* __restrict__ Wq, const float* __restrict__ Wk,
    const float* __restrict__ Wv, const float* __restrict__ Wo,
    u16* __restrict__ XQ, u16* __restrict__ XK, u16* __restrict__ XV,
    u16* __restrict__ WQB, u16* __restrict__ WKB, u16* __restrict__ WVB,
    u16* __restrict__ WOB) {
  int idx = blockIdx.x * 256 + threadIdx.x;  // one 8-elem item each
  const float* src; u16* dst; int i;
  if      (idx <  524288) { src = q;  dst = XQ;  i = idx; }
  else if (idx < 1048576) { src = k;  dst = XK;  i = idx -  524288; }
  else if (idx < 1572864) { src = v;  dst = XV;  i = idx - 1048576; }
  else if (idx < 1703936) { src = Wq; dst = WQB; i = idx - 1572864; }
  else if (idx < 1835008) { src = Wk; dst = WKB; i = idx - 1703936; }
  else if (idx < 1966080) { src = Wv; dst = WVB; i = idx - 1835008; }
  else                    { src = Wo; dst = WOB; i = idx - 1966080; }
  const float4* p = (const float4*)src + (size_t)i * 2;
  float4 a = p[0], b = p[1];
  union { u16 us[8]; uint4 vv; } u;
  u.us[0] = bf16_rne(a.x); u.us[1] = bf16_rne(a.y);
  u.us[2] = bf16_rne(a.z); u.us[3] = bf16_rne(a.w);
  u.us[4] = bf16_rne(b.x); u.us[5] = bf16_rne(b.y);
  u.us[6] = bf16_rne(b.z); u.us[7] = bf16_rne(b.w);
  ((uint4*)dst)[i] = u.vv;
}

// ---------------- fused QKV projection GEMM (768 blocks, 128x128, dbuf) ------
// T1 swizzle: xcd = bx&7 owns bm-stripe xcd*4..+3 for all segs; seg-major,
// bn fastest -> per XCD: A-panels (4bm x 3seg x 256KB) + W-seg L2-resident.
__global__ __launch_bounds__(256, 3) void gemm_qkv(
    const u16* __restrict__ XQ, const u16* __restrict__ XK, const u16* __restrict__ XV,
    const u16* __restrict__ Wb,  // WQ|WK|WV contiguous, 1M elems apart
    const float* __restrict__ bq, const float* __restrict__ bkb, const float* __restrict__ bv,
    const float* __restrict__ gate,
    u16* __restrict__ QB, u16* __restrict__ KB, u16* __restrict__ VTB) {
  __shared__ __attribute__((aligned(16))) u16 As[2][128 * 32];
  __shared__ __attribute__((aligned(16))) u16 Bs[2][128 * 32];
  const int t = threadIdx.x, lane = t & 63, w = t >> 6;
  const int l15 = lane & 15, quad = lane >> 4;
  const int xcd = blockIdx.x & 7, idx = blockIdx.x >> 3;
  const int seg = idx >> 5, r5 = idx & 31;
  const int bm = (xcd << 2) + (r5 >> 3), bn = r5 & 7;
  const int m0 = bm << 7, n0 = bn << 7;
  const u16* A = (seg == 0) ? XQ : (seg == 1) ? XK : XV;
  const u16* W = Wb + (long)seg * 1048576;
  const int wm = (w >> 1) << 6, wn = (w & 1) << 6;
  const int r0 = t >> 2, cc0 = (t & 3) * 8;
  const u16* gA0 = A + (long)(m0 + r0) * 1024 + cc0;
  const u16* gA1 = gA0 + 64 * 1024;
  const u16* gB0 = W + (long)(n0 + r0) * 1024 + cc0;
  const u16* gB1 = gB0 + 64 * 1024;

  async16(gA0, &As[0][t * 8]); async16(gA1, &As[0][(t + 256) * 8]);
  async16(gB0, &Bs[0][t * 8]); async16(gB1, &Bs[0][(t + 256) * 8]);

  f32x4 acc[4][4] = {};
  for (int k0 = 0; k0 < 1024; k0 += 32) {
    const int cur = (k0 >> 5) & 1;
    __syncthreads();
    if (k0 + 32 < 1024) {
      const int kn = k0 + 32, nb = cur ^ 1;
      async16(gA0 + kn, &As[nb][t * 8]); async16(gA1 + kn, &As[nb][(t + 256) * 8]);
      async16(gB0 + kn, &Bs[nb][t * 8]); async16(gB1 + kn, &Bs[nb][(t + 256) * 8]);
    }
    bf16x8 af[4], bfm[4];
#pragma unroll
    for (int i = 0; i < 4; i++)
      af[i] = *(const bf16x8*)&As[cur][(wm + i * 16 + l15) * 32 + quad * 8];
#pragma unroll
    for (int j = 0; j < 4; j++)
      bfm[j] = *(const bf16x8*)&Bs[cur][(wn + j * 16 + l15) * 32 + quad * 8];
#pragma unroll
    for (int i = 0; i < 4; i++)
#pragma unroll
      for (int j = 0; j < 4; j++)
        acc[i][j] = __builtin_amdgcn_mfma_f32_16x16x32_bf16(af[i], bfm[j], acc[i][j], 0, 0, 0);
  }

  if (seg == 2) {  // V: bias + transposed write V^T[(b*1024+col)*2048 + n]
#pragma unroll
    for (int i = 0; i < 4; i++) {
      int token = m0 + wm + i * 16 + quad * 4;
      int bb_ = token >> 11, n = token & 2047;
#pragma unroll
      for (int j = 0; j < 4; j++) {
        int col = n0 + wn + j * 16 + l15;
        float bb = bv[col];
        union { u16 us[4]; uint2 u2; } pk;
#pragma unroll
        for (int r = 0; r < 4; r++) pk.us[r] = bf16_rne(acc[i][j][r] + bb);
        *(uint2*)&VTB[(long)(bb_ * 1024 + col) * 2048 + n] = pk.u2;
      }
    }
  } else {
    const float* bias = seg ? bkb : bq;
    u16* C = seg ? KB : QB;
#pragma unroll
    for (int j = 0; j < 4; j++) {
      int col = n0 + wn + j * 16 + l15;
      float bb = bias[col];
      float scl = 1.f;
      if (seg == 0) {
        float g = gate[col >> 6];
        float sig = 1.f / (1.f + __builtin_amdgcn_exp2f(-g * 1.44269504f));
        scl = sig * 0.125f * 1.44269504f;
      }
#pragma unroll
      for (int i = 0; i < 4; i++) {
        int row = m0 + wm + i * 16 + quad * 4;
#pragma unroll
        for (int r = 0; r < 4; r++)
          C[(long)(row + r) * 1024 + col] = bf16_rne((acc[i][j][r] + bb) * scl);
      }
    }
  }
}

// ---------------- out-proj GEMM: 64x128 tiles, dbuf, fp32 out ----------------
// T1 swizzle: xcd owns bm-stripe xcd*8..+7, bn fastest.
__global__ __launch_bounds__(256, 2) void gemm_out(
    const u16* __restrict__ A, const u16* __restrict__ W,
    const float* __restrict__ bias, float* __restrict__ Cf) {
  __shared__ __attribute__((aligned(16))) u16 As[2][64 * 32];
  __shared__ __attribute__((aligned(16))) u16 Bs[2][128 * 32];
  const int t = threadIdx.x, lane = t & 63, w = t >> 6;
  const int l15 = lane & 15, quad = lane >> 4;
  const int xcd = blockIdx.x & 7, idx = blockIdx.x >> 3;
  const int bm = (xcd << 3) + (idx >> 3), bn = idx & 7;
  const int m0 = bm << 6, n0 = bn << 7;
  const int wm = (w >> 1) << 5, wn = (w & 1) << 6;
  const int r0 = t >> 2, cc0 = (t & 3) * 8;
  const u16* gA = A + (long)(m0 + r0) * 1024 + cc0;
  const u16* gB0 = W + (long)(n0 + r0) * 1024 + cc0;
  const u16* gB1 = gB0 + 64 * 1024;

  async16(gA, &As[0][t * 8]);
  async16(gB0, &Bs[0][t * 8]); async16(gB1, &Bs[0][(t + 256) * 8]);

  f32x4 acc[2][4] = {};
  for (int k0 = 0; k0 < 1024; k0 += 32) {
    const int cur = (k0 >> 5) & 1;
    __syncthreads();
    if (k0 + 32 < 1024) {
      const int kn = k0 + 32, nb = cur ^ 1;
      async16(gA + kn, &As[nb][t * 8]);
      async16(gB0 + kn, &Bs[nb][t * 8]); async16(gB1 + kn, &Bs[nb][(t + 256) * 8]);
    }
    bf16x8 af[2], bfm[4];
#pragma unroll
    for (int i = 0; i < 2; i++)
      af[i] = *(const bf16x8*)&As[cur][(wm + i * 16 + l15) * 32 + quad * 8];
#pragma unroll
    for (int j = 0; j < 4; j++)
      bfm[j] = *(const bf16x8*)&Bs[cur][(wn + j * 16 + l15) * 32 + quad * 8];
#pragma unroll
    for (int i = 0; i < 2; i++)
#pragma unroll
      for (int j = 0; j < 4; j++)
        acc[i][j] = __builtin_amdgcn_mfma_f32_16x16x32_bf16(af[i], bfm[j], acc[i][j], 0, 0, 0);
  }

#pragma unroll
  for (int j = 0; j < 4; j++) {
    int col = n0 + wn + j * 16 + l15;
    float bb = bias[col];
#pragma unroll
    for (int i = 0; i < 2; i++) {
      int row = m0 + wm + i * 16 + quad * 4;
#pragma unroll
      for (int r = 0; r < 4; r++)
        Cf[(long)(row + r) * 1024 + col] = acc[i][j][r] + bb;
    }
  }
}

// ---------------- split-K x4 flash attention, swapped QK^T, P in-register ----
// grid (128,16,2) x 128 thr: bx = qt*4 + ksp; 2 waves x 32 q-rows, BK=32,
// 16 kt iters over 512 keys. QK: s = mfma(A=K rows 2*l15+j, B=Q) = S^T; lane
// (l15,quad) holds q=i*16+l15, keys 8*quad+2r+j == its PV A-frag keys ->
// P packed in-register via v_cvt_pk_bf16_f32, no P LDS round-trip.
// LDS 16KB -> 10 blocks/CU; grid 16/CU demand keeps 10 resident (was 8).
__global__ __launch_bounds__(128, 5) void attn_kernel(
    const u16* __restrict__ Q, const u16* __restrict__ Kb,
    const u16* __restrict__ Vt, u16* __restrict__ Op0, u16* __restrict__ Op3,
    float* __restrict__ lp) {
  __shared__ __attribute__((aligned(16))) u16 Ks[2][32 * 64];  // [key][d], 128B rows
  __shared__ __attribute__((aligned(16))) u16 Vs[2][64 * 32];  // [d][key], 64B rows
  const int t = threadIdx.x, lane = t & 63, w = t >> 6;
  const int l15 = lane & 15, quad = lane >> 4;
  const int qt = blockIdx.x >> 2, ksp = blockIdx.x & 3;
  const int h = blockIdx.y, b = blockIdx.z;
  const int q0 = qt * 64, tok0 = b * 2048, key0 = ksp * 512;
  const u16* Kbase = Kb + (long)tok0 * 1024 + h * 64;
  const u16* Vbase = Vt + (long)(b * 1024 + h * 64) * 2048 + key0;

  // loop-invariant Q fragments (B operand; wave rows q0 + w*32 .. +31)
  bf16x8 aq[2][2];
#pragma unroll
  for (int i = 0; i < 2; i++) {
    long row = tok0 + q0 + w * 32 + i * 16 + l15;
#pragma unroll
    for (int ks = 0; ks < 2; ks++)
      aq[i][ks] = *(const bf16x8*)&Q[row * 1024 + h * 64 + ks * 32 + quad * 8];
  }

  // stage kt=0. K: chunk ^ ((row>>1)&7); V: chunk ^ ((row>>1)&3). Swizzle on
  // the GLOBAL chunk so global_load_lds lane-contiguity holds.
#pragma unroll
  for (int i = 0; i < 2; i++) {
    int c = i * 128 + t;
    int rk = c >> 3, ck = c & 7, cks = ck ^ ((rk >> 1) & 7);
    async16(&Kbase[(long)(key0 + rk) * 1024 + cks * 8], &Ks[0][c * 8]);
    int rv = c >> 2, cv = c & 3, cvs = cv ^ ((rv >> 1) & 3);
    async16(&Vbase[(long)rv * 2048 + cvs * 8], &Vs[0][c * 8]);
  }

  float l_st[2] = {};   // per-lane partial over this lane's keys
  f32x4 O[2][4] = {};

  for (int kt = 0; kt < 16; kt++) {
    const int cur = kt & 1;
    __syncthreads();
    if (kt + 1 < 16) {
      const int kk = (kt + 1) * 32, nb = cur ^ 1;
#pragma unroll
      for (int i = 0; i < 2; i++) {
        int c = i * 128 + t;
        int rk = c >> 3, ck = c & 7, cks = ck ^ ((rk >> 1) & 7);
        async16(&Kbase[(long)(key0 + kk + rk) * 1024 + cks * 8], &Ks[nb][c * 8]);
        int rv = c >> 2, cv = c & 3, cvs = cv ^ ((rv >> 1) & 3);
        async16(&Vbase[(long)rv * 2048 + kk + cvs * 8], &Vs[nb][c * 8]);
      }
    }

    // S^T = K Q^T (exp2 domain): A = K rows 2*l15+j, B = aq.
    f32x4 s[2][2] = {};
    __builtin_amdgcn_s_setprio(1);
#pragma unroll
    for (int ks = 0; ks < 2; ks++) {
      bf16x8 bk_[2];
#pragma unroll
      for (int j = 0; j < 2; j++) {
        int rl = 2 * l15 + j;
        bk_[j] = *(const bf16x8*)&Ks[cur][rl * 64 + (((ks * 4 + quad) ^ (l15 & 7))) * 8];
      }
#pragma unroll
      for (int i = 0; i < 2; i++)
#pragma unroll
        for (int j = 0; j < 2; j++)
          s[i][j] = __builtin_amdgcn_mfma_f32_16x16x32_bf16(bk_[j], aq[i][ks], s[i][j], 0, 0, 0);
    }
    __builtin_amdgcn_s_setprio(0);

    // exp2 + in-register pack via cvt_pk: ap[i] word r = keys (8q+2r, 8q+2r+1)
    bf16x8 ap[2];
#pragma unroll
    for (int i = 0; i < 2; i++) {
      union { unsigned uw[4]; bf16x8 v8; } pw;
#pragma unroll
      for (int r = 0; r < 4; r++) {
        float p0 = __builtin_amdgcn_exp2f(s[i][0][r]);
        float p1 = __builtin_amdgcn_exp2f(s[i][1][r]);
        l_st[i] += p0 + p1;
        pw.uw[r] = cvtpk(p0, p1);
      }
      ap[i] = pw.v8;
    }

    // V fragments from LDS; O += P @ V (single K=32 MFMA pass)
    bf16x8 bv_[4];
#pragma unroll
    for (int dj = 0; dj < 4; dj++) {
      int rl = dj * 16 + l15;
      bv_[dj] = *(const bf16x8*)&Vs[cur][rl * 32 + ((quad ^ ((rl >> 1) & 3))) * 8];
    }
    __builtin_amdgcn_s_setprio(1);
#pragma unroll
    for (int i = 0; i < 2; i++)
#pragma unroll
      for (int dj = 0; dj < 4; dj++)
        O[i][dj] = __builtin_amdgcn_mfma_f32_16x16x32_bf16(ap[i], bv_[dj], O[i][dj], 0, 0, 0);
    __builtin_amdgcn_s_setprio(0);
  }

  // epilogue: l reduced across quads; store O (bf16) + l (f32)
  u16* dst = (ksp == 3) ? Op3 : (Op0 + (long)ksp * 4194304);
#pragma unroll
  for (int i = 0; i < 2; i++) {
    float ls = l_st[i];
    ls += __shfl_xor(ls, 16); ls += __shfl_xor(ls, 32);
    if (quad == 0) {
      long qrow = tok0 + q0 + w * 32 + i * 16 + l15;
      lp[ksp * 65536 + (int)qrow * 16 + h] = ls;
    }
#pragma unroll
    for (int r = 0; r < 4; r++) {
      long row = tok0 + q0 + w * 32 + i * 16 + quad * 4 + r;
#pragma unroll
      for (int dj = 0; dj < 4; dj++)
        dst[row * 1024 + h * 64 + dj * 16 + l15] = cvt16(O[i][dj][r]);
    }
  }
}

// ---------------- merge split-K partials: AO = (O0+..+O3)/(l0+..+l3) --------
// AO aliases partial 0 (per-thread read-before-write, 1:1 map -> safe).
__global__ __launch_bounds__(256) void merge_kernel(
    const u16* __restrict__ Op0, const u16* __restrict__ Op3,
    const float* __restrict__ lp, u16* __restrict__ AO) {
  int idx = blockIdx.x * 256 + threadIdx.x;  // 524288 chunks of 8 elems
  int tok = idx >> 7, rem = idx & 127, h = rem >> 3;
  int li = tok * 16 + h;
  float inv = 1.f / (lp[li] + lp[65536 + li] + lp[131072 + li] + lp[196608 + li]);
  union U { uint4 v; u16 us[8]; };
  U a0, a1, a2, a3, uo;
  a0.v = ((const uint4*)Op0)[idx];
  a1.v = ((const uint4*)Op0)[idx + 524288];
  a2.v = ((const uint4*)Op0)[idx + 1048576];
  a3.v = ((const uint4*)Op3)[idx];
#pragma unroll
  for (int j = 0; j < 8; j++) {
    float f0 = __builtin_bit_cast(float, (unsigned)((unsigned)a0.us[j] << 16));
    float f1 = __builtin_bit_cast(float, (unsigned)((unsigned)a1.us[j] << 16));
    float f2 = __builtin_bit_cast(float, (unsigned)((unsigned)a2.us[j] << 16));
    float f3 = __builtin_bit_cast(float, (unsigned)((unsigned)a3.us[j] << 16));
    uo.us[j] = cvt16((f0 + f1 + f2 + f3) * inv);
  }
  ((uint4*)AO)[idx] = uo.v;
}

extern "C" void kernel_launch(void* const* d_in, const int* in_sizes, int n_in,
                              void* d_out, int out_size, void* d_ws, size_t ws_size,
                              hipStream_t stream) {
  const float* q  = (const float*)d_in[0];
  const float* k  = (const float*)d_in[1];
  const float* v  = (const float*)d_in[2];
  const float* Wq = (const float*)d_in[3];
  const float* bq = (const float*)d_in[4];
  const float* Wk = (const float*)d_in[5];
  const float* bk = (const float*)d_in[6];
  const float* Wv = (const float*)d_in[7];
  const float* bv = (const float*)d_in[8];
  const float* Wo = (const float*)d_in[9];
  const float* bo = (const float*)d_in[10];
  const float* gate = (const float*)d_in[11];
  float* out = (float*)d_out;
  char* ws = (char*)d_ws;

  const size_t MB = 1u << 20;
  u16* WQB = (u16*)(ws + 0 * MB);   // WQ|WK|WV|WO contiguous (2MB each)
  u16* WKB = (u16*)(ws + 2 * MB);
  u16* WVB = (u16*)(ws + 4 * MB);
  u16* WOB = (u16*)(ws + 6 * MB);
  u16* XQ  = (u16*)(ws + 8 * MB);
  u16* XK  = (u16*)(ws + 16 * MB);
  u16* XV  = (u16*)(ws + 24 * MB);
  u16* QB  = (u16*)(ws + 32 * MB);
  u16* KB  = (u16*)(ws + 40 * MB);
  u16* OPp  = (u16*)(ws + 8 * MB);             // partials 0-2 (24MB over dead XQ/XK/XV)
  u16* OPd3 = (u16*)((char*)d_out + 8 * MB);   // partial 3 in d_out's upper half
  float* LP = (float*)(ws + 0 * MB);           // 1MB partial l (over dead WQB)
  u16* AOB  = (u16*)(ws + 8 * MB);             // == partial 0 (merge self-overwrite)
  u16* VTB  = (u16*)d_out;                     // d_out low 8MB as V^T scratch

  cast_all<<<8192, 256, 0, stream>>>(q, k, v, Wq, Wk, Wv, Wo,
                                     XQ, XK, XV, WQB, WKB, WVB, WOB);
  gemm_qkv<<<768, 256, 0, stream>>>(XQ, XK, XV, WQB, bq, bk, bv, gate, QB, KB, VTB);
  attn_kernel<<<dim3(128, 16, 2), 128, 0, stream>>>(QB, KB, VTB, OPp, OPd3, LP);
  merge_kernel<<<2048, 256, 0, stream>>>(OPp, OPd3, LP, AOB);
  gemm_out<<<512, 256, 0, stream>>>(AOB, WOB, bo, out);
}

// Round 4
// 230.466 us; speedup vs baseline: 1.2475x; 1.0093x over previous
//
#include <hip/hip_runtime.h>
#include <hip/hip_bf16.h>
#include <cstdint>

// GatedMultiheadAttention: B=2, N=2048, E=1024, H=16, D=64
// R11 = R10 with attn reworked for LDS-read reuse:
//  - 64 q-rows per wave (i=4), 128 per block: same 8KB LDS frag reads per
//    iter now feed 32 MFMAs (was 16) -> LDS-read B/FLOP halves (was
//    co-saturating: 31 B/KFLOP * 34.3 GFLOP / 16.5us MFMA-floor = 65 TB/s
//    ~ 69 TB/s LDS ceiling). Blocks halve -> staging traffic halves too.
//  - VGPR ~160 (aq 32 + O 64 + s 32 + transients) -> 3 waves/SIMD, matching
//    the occupancy we already measured (33%); launch_bounds(128,3).
//  - XCD-aware bx remap: xcd-pair owns one ksp (K/V working set ~8MB stays
//    L2-local per XCD; bx&7 == linear%8 since gridDim.x=64 => 64h%8==0).
// ws (48MB): weights 0-8, XQ 8-16, XK/XV 16-32 (-> OPp partials + AOB),
// QB 32-40, KB 40-48. d_out: VTB low 8MB, partial3 high 8MB.

#define DEV __device__ __forceinline__
typedef __attribute__((ext_vector_type(8))) short bf16x8;
typedef __attribute__((ext_vector_type(4))) float f32x4;
typedef unsigned short u16;

DEV void async16(const void* g, void* l) {
  __builtin_amdgcn_global_load_lds(
      (const __attribute__((address_space(1))) unsigned int*)g,
      (__attribute__((address_space(3))) unsigned int*)l, 16, 0, 0);
}

DEV u16 bf16_rne(float f) {
  unsigned int u = __builtin_bit_cast(unsigned int, f);
  u += 0x7FFFu + ((u >> 16) & 1u);
  return (u16)(u >> 16);
}

DEV u16 cvt16(float x) {
  __hip_bfloat16 h = __float2bfloat16(x);
  return __builtin_bit_cast(u16, h);
}

// packed RNE f32x2 -> bf16x2 in one VALU op (low = lo, high = hi)
DEV unsigned cvtpk(float lo, float hi) {
  unsigned r;
  asm("v_cvt_pk_bf16_f32 %0, %1, %2" : "=v"(r) : "v"(lo), "v"(hi));
  return r;
}

// ---------------- one fused cast: q,k,v + 4 weights ----------------
__global__ __launch_bounds__(256) void cast_all(
    const float* __restrict__ q, const float* __restrict__ k, const float* __restrict__ v,
    const float* __restrict__ Wq, const float* __restrict__ Wk,
    const float* __restrict__ Wv, const float* __restrict__ Wo,
    u16* __restrict__ XQ, u16* __restrict__ XK, u16* __restrict__ XV,
    u16* __restrict__ WQB, u16* __restrict__ WKB, u16* __restrict__ WVB,
    u16* __restrict__ WOB) {
  int idx = blockIdx.x * 256 + threadIdx.x;  // one 8-elem item each
  const float* src; u16* dst; int i;
  if      (idx <  524288) { src = q;  dst = XQ;  i = idx; }
  else if (idx < 1048576) { src = k;  dst = XK;  i = idx -  524288; }
  else if (idx < 1572864) { src = v;  dst = XV;  i = idx - 1048576; }
  else if (idx < 1703936) { src = Wq; dst = WQB; i = idx - 1572864; }
  else if (idx < 1835008) { src = Wk; dst = WKB; i = idx - 1703936; }
  else if (idx < 1966080) { src = Wv; dst = WVB; i = idx - 1835008; }
  else                    { src = Wo; dst = WOB; i = idx - 1966080; }
  const float4* p = (const float4*)src + (size_t)i * 2;
  float4 a = p[0], b = p[1];
  union { u16 us[8]; uint4 vv; } u;
  u.us[0] = bf16_rne(a.x); u.us[1] = bf16_rne(a.y);
  u.us[2] = bf16_rne(a.z); u.us[3] = bf16_rne(a.w);
  u.us[4] = bf16_rne(b.x); u.us[5] = bf16_rne(b.y);
  u.us[6] = bf16_rne(b.z); u.us[7] = bf16_rne(b.w);
  ((uint4*)dst)[i] = u.vv;
}

// ---------------- fused QKV projection GEMM (768 blocks, 128x128, dbuf) ------
// T1 swizzle: xcd = bx&7 owns bm-stripe xcd*4..+3 for all segs; seg-major,
// bn fastest -> per XCD: A-panels (4bm x 3seg x 256KB) + W-seg L2-resident.
__global__ __launch_bounds__(256, 3) void gemm_qkv(
    const u16* __restrict__ XQ, const u16* __restrict__ XK, const u16* __restrict__ XV,
    const u16* __restrict__ Wb,  // WQ|WK|WV contiguous, 1M elems apart
    const float* __restrict__ bq, const float* __restrict__ bkb, const float* __restrict__ bv,
    const float* __restrict__ gate,
    u16* __restrict__ QB, u16* __restrict__ KB, u16* __restrict__ VTB) {
  __shared__ __attribute__((aligned(16))) u16 As[2][128 * 32];
  __shared__ __attribute__((aligned(16))) u16 Bs[2][128 * 32];
  const int t = threadIdx.x, lane = t & 63, w = t >> 6;
  const int l15 = lane & 15, quad = lane >> 4;
  const int xcd = blockIdx.x & 7, idx = blockIdx.x >> 3;
  const int seg = idx >> 5, r5 = idx & 31;
  const int bm = (xcd << 2) + (r5 >> 3), bn = r5 & 7;
  const int m0 = bm << 7, n0 = bn << 7;
  const u16* A = (seg == 0) ? XQ : (seg == 1) ? XK : XV;
  const u16* W = Wb + (long)seg * 1048576;
  const int wm = (w >> 1) << 6, wn = (w & 1) << 6;
  const int r0 = t >> 2, cc0 = (t & 3) * 8;
  const u16* gA0 = A + (long)(m0 + r0) * 1024 + cc0;
  const u16* gA1 = gA0 + 64 * 1024;
  const u16* gB0 = W + (long)(n0 + r0) * 1024 + cc0;
  const u16* gB1 = gB0 + 64 * 1024;

  async16(gA0, &As[0][t * 8]); async16(gA1, &As[0][(t + 256) * 8]);
  async16(gB0, &Bs[0][t * 8]); async16(gB1, &Bs[0][(t + 256) * 8]);

  f32x4 acc[4][4] = {};
  for (int k0 = 0; k0 < 1024; k0 += 32) {
    const int cur = (k0 >> 5) & 1;
    __syncthreads();
    if (k0 + 32 < 1024) {
      const int kn = k0 + 32, nb = cur ^ 1;
      async16(gA0 + kn, &As[nb][t * 8]); async16(gA1 + kn, &As[nb][(t + 256) * 8]);
      async16(gB0 + kn, &Bs[nb][t * 8]); async16(gB1 + kn, &Bs[nb][(t + 256) * 8]);
    }
    bf16x8 af[4], bfm[4];
#pragma unroll
    for (int i = 0; i < 4; i++)
      af[i] = *(const bf16x8*)&As[cur][(wm + i * 16 + l15) * 32 + quad * 8];
#pragma unroll
    for (int j = 0; j < 4; j++)
      bfm[j] = *(const bf16x8*)&Bs[cur][(wn + j * 16 + l15) * 32 + quad * 8];
#pragma unroll
    for (int i = 0; i < 4; i++)
#pragma unroll
      for (int j = 0; j < 4; j++)
        acc[i][j] = __builtin_amdgcn_mfma_f32_16x16x32_bf16(af[i], bfm[j], acc[i][j], 0, 0, 0);
  }

  if (seg == 2) {  // V: bias + transposed write V^T[(b*1024+col)*2048 + n]
#pragma unroll
    for (int i = 0; i < 4; i++) {
      int token = m0 + wm + i * 16 + quad * 4;
      int bb_ = token >> 11, n = token & 2047;
#pragma unroll
      for (int j = 0; j < 4; j++) {
        int col = n0 + wn + j * 16 + l15;
        float bb = bv[col];
        union { u16 us[4]; uint2 u2; } pk;
#pragma unroll
        for (int r = 0; r < 4; r++) pk.us[r] = bf16_rne(acc[i][j][r] + bb);
        *(uint2*)&VTB[(long)(bb_ * 1024 + col) * 2048 + n] = pk.u2;
      }
    }
  } else {
    const float* bias = seg ? bkb : bq;
    u16* C = seg ? KB : QB;
#pragma unroll
    for (int j = 0; j < 4; j++) {
      int col = n0 + wn + j * 16 + l15;
      float bb = bias[col];
      float scl = 1.f;
      if (seg == 0) {
        float g = gate[col >> 6];
        float sig = 1.f / (1.f + __builtin_amdgcn_exp2f(-g * 1.44269504f));
        scl = sig * 0.125f * 1.44269504f;
      }
#pragma unroll
      for (int i = 0; i < 4; i++) {
        int row = m0 + wm + i * 16 + quad * 4;
#pragma unroll
        for (int r = 0; r < 4; r++)
          C[(long)(row + r) * 1024 + col] = bf16_rne((acc[i][j][r] + bb) * scl);
      }
    }
  }
}

// ---------------- out-proj GEMM: 64x128 tiles, dbuf, fp32 out ----------------
// T1 swizzle: xcd owns bm-stripe xcd*8..+7, bn fastest.
__global__ __launch_bounds__(256, 2) void gemm_out(
    const u16* __restrict__ A, const u16* __restrict__ W,
    const float* __restrict__ bias, float* __restrict__ Cf) {
  __shared__ __attribute__((aligned(16))) u16 As[2][64 * 32];
  __shared__ __attribute__((aligned(16))) u16 Bs[2][128 * 32];
  const int t = threadIdx.x, lane = t & 63, w = t >> 6;
  const int l15 = lane & 15, quad = lane >> 4;
  const int xcd = blockIdx.x & 7, idx = blockIdx.x >> 3;
  const int bm = (xcd << 3) + (idx >> 3), bn = idx & 7;
  const int m0 = bm << 6, n0 = bn << 7;
  const int wm = (w >> 1) << 5, wn = (w & 1) << 6;
  const int r0 = t >> 2, cc0 = (t & 3) * 8;
  const u16* gA = A + (long)(m0 + r0) * 1024 + cc0;
  const u16* gB0 = W + (long)(n0 + r0) * 1024 + cc0;
  const u16* gB1 = gB0 + 64 * 1024;

  async16(gA, &As[0][t * 8]);
  async16(gB0, &Bs[0][t * 8]); async16(gB1, &Bs[0][(t + 256) * 8]);

  f32x4 acc[2][4] = {};
  for (int k0 = 0; k0 < 1024; k0 += 32) {
    const int cur = (k0 >> 5) & 1;
    __syncthreads();
    if (k0 + 32 < 1024) {
      const int kn = k0 + 32, nb = cur ^ 1;
      async16(gA + kn, &As[nb][t * 8]);
      async16(gB0 + kn, &Bs[nb][t * 8]); async16(gB1 + kn, &Bs[nb][(t + 256) * 8]);
    }
    bf16x8 af[2], bfm[4];
#pragma unroll
    for (int i = 0; i < 2; i++)
      af[i] = *(const bf16x8*)&As[cur][(wm + i * 16 + l15) * 32 + quad * 8];
#pragma unroll
    for (int j = 0; j < 4; j++)
      bfm[j] = *(const bf16x8*)&Bs[cur][(wn + j * 16 + l15) * 32 + quad * 8];
#pragma unroll
    for (int i = 0; i < 2; i++)
#pragma unroll
      for (int j = 0; j < 4; j++)
        acc[i][j] = __builtin_amdgcn_mfma_f32_16x16x32_bf16(af[i], bfm[j], acc[i][j], 0, 0, 0);
  }

#pragma unroll
  for (int j = 0; j < 4; j++) {
    int col = n0 + wn + j * 16 + l15;
    float bb = bias[col];
#pragma unroll
    for (int i = 0; i < 2; i++) {
      int row = m0 + wm + i * 16 + quad * 4;
#pragma unroll
      for (int r = 0; r < 4; r++)
        Cf[(long)(row + r) * 1024 + col] = acc[i][j][r] + bb;
    }
  }
}

// ---------------- split-K x4 flash attention, 64 q-rows/wave ----------------
// grid (64,16,2) x 128 thr. xcd = bx&7; ksp = xcd>>1 (xcd-pair owns a
// key-split), qt = ((xcd&1)<<3)|(bx>>3). 2 waves x 64 q-rows (i=4), BK=32,
// 16 iters over 512 keys. QK: s = mfma(A=K rows 2*l15+j, B=Q) = S^T; lane
// (l15,quad) holds q=i*16+l15, keys 8*quad+2r+j == its PV A-frag keys ->
// P packed in-register via v_cvt_pk_bf16_f32, no P LDS round-trip.
// Same 8KB LDS frag reads/iter now feed 32 MFMAs (2x reuse vs R10).
__global__ __launch_bounds__(128, 3) void attn_kernel(
    const u16* __restrict__ Q, const u16* __restrict__ Kb,
    const u16* __restrict__ Vt, u16* __restrict__ Op0, u16* __restrict__ Op3,
    float* __restrict__ lp) {
  __shared__ __attribute__((aligned(16))) u16 Ks[2][32 * 64];  // [key][d], 128B rows
  __shared__ __attribute__((aligned(16))) u16 Vs[2][64 * 32];  // [d][key], 64B rows
  const int t = threadIdx.x, lane = t & 63, w = t >> 6;
  const int l15 = lane & 15, quad = lane >> 4;
  const int xcd = blockIdx.x & 7, rr = blockIdx.x >> 3;
  const int ksp = xcd >> 1, qt = ((xcd & 1) << 3) | rr;
  const int h = blockIdx.y, b = blockIdx.z;
  const int q0 = qt * 128, tok0 = b * 2048, key0 = ksp * 512;
  const u16* Kbase = Kb + (long)tok0 * 1024 + h * 64;
  const u16* Vbase = Vt + (long)(b * 1024 + h * 64) * 2048 + key0;

  // loop-invariant Q fragments (B operand; wave rows q0 + w*64 .. +63)
  bf16x8 aq[4][2];
#pragma unroll
  for (int i = 0; i < 4; i++) {
    long row = tok0 + q0 + w * 64 + i * 16 + l15;
#pragma unroll
    for (int ks = 0; ks < 2; ks++)
      aq[i][ks] = *(const bf16x8*)&Q[row * 1024 + h * 64 + ks * 32 + quad * 8];
  }

  // stage kt=0. K: chunk ^ ((row>>1)&7); V: chunk ^ ((row>>1)&3). Swizzle on
  // the GLOBAL chunk so global_load_lds lane-contiguity holds.
#pragma unroll
  for (int i = 0; i < 2; i++) {
    int c = i * 128 + t;
    int rk = c >> 3, ck = c & 7, cks = ck ^ ((rk >> 1) & 7);
    async16(&Kbase[(long)(key0 + rk) * 1024 + cks * 8], &Ks[0][c * 8]);
    int rv = c >> 2, cv = c & 3, cvs = cv ^ ((rv >> 1) & 3);
    async16(&Vbase[(long)rv * 2048 + cvs * 8], &Vs[0][c * 8]);
  }

  float l_st[4] = {};   // per-lane partial over this lane's keys
  f32x4 O[4][4] = {};

  for (int kt = 0; kt < 16; kt++) {
    const int cur = kt & 1;
    __syncthreads();
    if (kt + 1 < 16) {
      const int kk = (kt + 1) * 32, nb = cur ^ 1;
#pragma unroll
      for (int i = 0; i < 2; i++) {
        int c = i * 128 + t;
        int rk = c >> 3, ck = c & 7, cks = ck ^ ((rk >> 1) & 7);
        async16(&Kbase[(long)(key0 + kk + rk) * 1024 + cks * 8], &Ks[nb][c * 8]);
        int rv = c >> 2, cv = c & 3, cvs = cv ^ ((rv >> 1) & 3);
        async16(&Vbase[(long)rv * 2048 + kk + cvs * 8], &Vs[nb][c * 8]);
      }
    }

    // S^T = K Q^T (exp2 domain): A = K rows 2*l15+j, B = aq. 16 MFMAs per
    // 4 b128 K-frag reads (each bk_ feeds all 4 i's).
    f32x4 s[4][2] = {};
    __builtin_amdgcn_s_setprio(1);
#pragma unroll
    for (int ks = 0; ks < 2; ks++) {
      bf16x8 bk_[2];
#pragma unroll
      for (int j = 0; j < 2; j++) {
        int rl = 2 * l15 + j;
        bk_[j] = *(const bf16x8*)&Ks[cur][rl * 64 + (((ks * 4 + quad) ^ (l15 & 7))) * 8];
      }
#pragma unroll
      for (int i = 0; i < 4; i++)
#pragma unroll
        for (int j = 0; j < 2; j++)
          s[i][j] = __builtin_amdgcn_mfma_f32_16x16x32_bf16(bk_[j], aq[i][ks], s[i][j], 0, 0, 0);
    }
    __builtin_amdgcn_s_setprio(0);

    // exp2 + in-register pack via cvt_pk: ap[i] word r = keys (8q+2r, 8q+2r+1)
    bf16x8 ap[4];
#pragma unroll
    for (int i = 0; i < 4; i++) {
      union { unsigned uw[4]; bf16x8 v8; } pw;
#pragma unroll
      for (int r = 0; r < 4; r++) {
        float p0 = __builtin_amdgcn_exp2f(s[i][0][r]);
        float p1 = __builtin_amdgcn_exp2f(s[i][1][r]);
        l_st[i] += p0 + p1;
        pw.uw[r] = cvtpk(p0, p1);
      }
      ap[i] = pw.v8;
    }

    // V fragments from LDS; O += P @ V: 16 MFMAs per 4 b128 V-frag reads.
    bf16x8 bv_[4];
#pragma unroll
    for (int dj = 0; dj < 4; dj++) {
      int rl = dj * 16 + l15;
      bv_[dj] = *(const bf16x8*)&Vs[cur][rl * 32 + ((quad ^ ((rl >> 1) & 3))) * 8];
    }
    __builtin_amdgcn_s_setprio(1);
#pragma unroll
    for (int i = 0; i < 4; i++)
#pragma unroll
      for (int dj = 0; dj < 4; dj++)
        O[i][dj] = __builtin_amdgcn_mfma_f32_16x16x32_bf16(ap[i], bv_[dj], O[i][dj], 0, 0, 0);
    __builtin_amdgcn_s_setprio(0);
  }

  // epilogue: l reduced across quads; store O (bf16) + l (f32)
  u16* dst = (ksp == 3) ? Op3 : (Op0 + (long)ksp * 4194304);
#pragma unroll
  for (int i = 0; i < 4; i++) {
    float ls = l_st[i];
    ls += __shfl_xor(ls, 16); ls += __shfl_xor(ls, 32);
    if (quad == 0) {
      long qrow = tok0 + q0 + w * 64 + i * 16 + l15;
      lp[ksp * 65536 + (int)qrow * 16 + h] = ls;
    }
#pragma unroll
    for (int r = 0; r < 4; r++) {
      long row = tok0 + q0 + w * 64 + i * 16 + quad * 4 + r;
#pragma unroll
      for (int dj = 0; dj < 4; dj++)
        dst[row * 1024 + h * 64 + dj * 16 + l15] = cvt16(O[i][dj][r]);
    }
  }
}

// ---------------- merge split-K partials: AO = (O0+..+O3)/(l0+..+l3) --------
// AO aliases partial 0 (per-thread read-before-write, 1:1 map -> safe).
__global__ __launch_bounds__(256) void merge_kernel(
    const u16* __restrict__ Op0, const u16* __restrict__ Op3,
    const float* __restrict__ lp, u16* __restrict__ AO) {
  int idx = blockIdx.x * 256 + threadIdx.x;  // 524288 chunks of 8 elems
  int tok = idx >> 7, rem = idx & 127, h = rem >> 3;
  int li = tok * 16 + h;
  float inv = 1.f / (lp[li] + lp[65536 + li] + lp[131072 + li] + lp[196608 + li]);
  union U { uint4 v; u16 us[8]; };
  U a0, a1, a2, a3, uo;
  a0.v = ((const uint4*)Op0)[idx];
  a1.v = ((const uint4*)Op0)[idx + 524288];
  a2.v = ((const uint4*)Op0)[idx + 1048576];
  a3.v = ((const uint4*)Op3)[idx];
#pragma unroll
  for (int j = 0; j < 8; j++) {
    float f0 = __builtin_bit_cast(float, (unsigned)((unsigned)a0.us[j] << 16));
    float f1 = __builtin_bit_cast(float, (unsigned)((unsigned)a1.us[j] << 16));
    float f2 = __builtin_bit_cast(float, (unsigned)((unsigned)a2.us[j] << 16));
    float f3 = __builtin_bit_cast(float, (unsigned)((unsigned)a3.us[j] << 16));
    uo.us[j] = cvt16((f0 + f1 + f2 + f3) * inv);
  }
  ((uint4*)AO)[idx] = uo.v;
}

extern "C" void kernel_launch(void* const* d_in, const int* in_sizes, int n_in,
                              void* d_out, int out_size, void* d_ws, size_t ws_size,
                              hipStream_t stream) {
  const float* q  = (const float*)d_in[0];
  const float* k  = (const float*)d_in[1];
  const float* v  = (const float*)d_in[2];
  const float* Wq = (const float*)d_in[3];
  const float* bq = (const float*)d_in[4];
  const float* Wk = (const float*)d_in[5];
  const float* bk = (const float*)d_in[6];
  const float* Wv = (const float*)d_in[7];
  const float* bv = (const float*)d_in[8];
  const float* Wo = (const float*)d_in[9];
  const float* bo = (const float*)d_in[10];
  const float* gate = (const float*)d_in[11];
  float* out = (float*)d_out;
  char* ws = (char*)d_ws;

  const size_t MB = 1u << 20;
  u16* WQB = (u16*)(ws + 0 * MB);   // WQ|WK|WV|WO contiguous (2MB each)
  u16* WKB = (u16*)(ws + 2 * MB);
  u16* WVB = (u16*)(ws + 4 * MB);
  u16* WOB = (u16*)(ws + 6 * MB);
  u16* XQ  = (u16*)(ws + 8 * MB);
  u16* XK  = (u16*)(ws + 16 * MB);
  u16* XV  = (u16*)(ws + 24 * MB);
  u16* QB  = (u16*)(ws + 32 * MB);
  u16* KB  = (u16*)(ws + 40 * MB);
  u16* OPp  = (u16*)(ws + 8 * MB);             // partials 0-2 (24MB over dead XQ/XK/XV)
  u16* OPd3 = (u16*)((char*)d_out + 8 * MB);   // partial 3 in d_out's upper half
  float* LP = (float*)(ws + 0 * MB);           // 1MB partial l (over dead WQB)
  u16* AOB  = (u16*)(ws + 8 * MB);             // == partial 0 (merge self-overwrite)
  u16* VTB  = (u16*)d_out;                     // d_out low 8MB as V^T scratch

  cast_all<<<8192, 256, 0, stream>>>(q, k, v, Wq, Wk, Wv, Wo,
                                     XQ, XK, XV, WQB, WKB, WVB, WOB);
  gemm_qkv<<<768, 256, 0, stream>>>(XQ, XK, XV, WQB, bq, bk, bv, gate, QB, KB, VTB);
  attn_kernel<<<dim3(64, 16, 2), 128, 0, stream>>>(QB, KB, VTB, OPp, OPd3, LP);
  merge_kernel<<<2048, 256, 0, stream>>>(OPp, OPd3, LP, AOB);
  gemm_out<<<512, 256, 0, stream>>>(AOB, WOB, bo, out);
}